// Round 1
// baseline (127.341 us; speedup 1.0000x reference)
//
#include <hip/hip_runtime.h>

#define N 64
#define MARGIN 0.1f

// One wave (64 lanes) per row. Lane i holds labels[row,i], scores[row,i].
// rank_i = #{k : label_k < label_i or (label_k == label_i and k < i)}  (stable argsort)
// ds_permute pushes score_i to lane rank_i  =>  lane j holds s_sorted[j].
// Row loss = sum_{i<j} max(0, s_i - s_j + MARGIN*(j-i)).
__global__ __launch_bounds__(256) void mmrl_kernel(const float* __restrict__ scores,
                                                   const float* __restrict__ labels,
                                                   float* __restrict__ out,
                                                   int rows) {
    const int lane = threadIdx.x & 63;
    const int wave_in_block = threadIdx.x >> 6;
    const int waves_per_block = blockDim.x >> 6;
    const int gwave = blockIdx.x * waves_per_block + wave_in_block;
    const int nwaves = gridDim.x * waves_per_block;

    float acc = 0.0f;

    for (int row = gwave; row < rows; row += nwaves) {
        const float lab = labels[row * N + lane];
        const float sc  = scores[row * N + lane];

        // --- stable rank of lab within the row ---
        int rank = 0;
        #pragma unroll
        for (int k = 0; k < N; ++k) {
            float lk = __shfl(lab, k, 64);
            rank += ((lk < lab) || (lk == lab && k < lane)) ? 1 : 0;
        }

        // --- scatter score to sorted position (ranks are a permutation) ---
        float s = __int_as_float(
            __builtin_amdgcn_ds_permute(rank << 2, __float_as_int(sc)));

        // --- pair loop: lane j accumulates over i < j ---
        // val = (s_i - MARGIN*i) + (MARGIN*j - s_j)
        const float t = MARGIN * (float)lane - s;
        #pragma unroll
        for (int i = 0; i < N - 1; ++i) {
            float si = __shfl(s, i, 64);
            float u  = si - MARGIN * (float)i;   // wave-uniform
            float v  = u + t;
            acc += (lane > i) ? fmaxf(v, 0.0f) : 0.0f;
        }
    }

    // --- wave reduction ---
    #pragma unroll
    for (int off = 32; off > 0; off >>= 1)
        acc += __shfl_down(acc, off, 64);

    __shared__ float wsum[8];
    if (lane == 0) wsum[wave_in_block] = acc;
    __syncthreads();
    if (threadIdx.x == 0) {
        float s = 0.0f;
        for (int w = 0; w < waves_per_block; ++w) s += wsum[w];
        atomicAdd(out, s * (1.0f / (float)rows));
    }
}

extern "C" void kernel_launch(void* const* d_in, const int* in_sizes, int n_in,
                              void* d_out, int out_size, void* d_ws, size_t ws_size,
                              hipStream_t stream) {
    const float* scores = (const float*)d_in[0];
    const float* labels = (const float*)d_in[1];
    float* out = (float*)d_out;
    const int rows = in_sizes[0] / N;   // 32768

    // harness poisons d_out with 0xAA before every timed launch
    hipMemsetAsync(out, 0, sizeof(float), stream);

    const int block = 256;                 // 4 waves/block
    const int grid  = 2048;                // 8192 waves, 4 rows each
    mmrl_kernel<<<grid, block, 0, stream>>>(scores, labels, out, rows);
}

// Round 2
// 95.931 us; speedup vs baseline: 1.3274x; 1.3274x over previous
//
#include <hip/hip_runtime.h>

#define N 64
#define MARGIN 0.1f
#define ROWS_PER_WAVE 4
#define WAVES_PER_BLOCK 4
// closed form: row_loss = sum_e u_e * (q_e - p_e)
//   p_e = #{k: lab_k < lab_e}            (label rank)
//   u_e = sc_e - MARGIN * p_e
//   q_e = #{k: u_k < u_e}                (u rank)
// derived from max(0,x) = (x+|x|)/2 summed over all pairs.

__global__ __launch_bounds__(256) void mmrl_kernel(const float* __restrict__ scores,
                                                   const float* __restrict__ labels,
                                                   float* __restrict__ out,
                                                   int rows) {
    __shared__ float lbuf[WAVES_PER_BLOCK][N];
    __shared__ float ubuf[WAVES_PER_BLOCK][N];
    __shared__ float wsum[WAVES_PER_BLOCK];

    const int lane = threadIdx.x & 63;
    const int w    = threadIdx.x >> 6;
    const int gwave = blockIdx.x * WAVES_PER_BLOCK + w;
    const int row0 = gwave * ROWS_PER_WAVE;

    // prefetch all rows for this wave (coalesced 256B per load)
    float lab[ROWS_PER_WAVE], sc[ROWS_PER_WAVE];
    #pragma unroll
    for (int r = 0; r < ROWS_PER_WAVE; ++r) {
        int row = row0 + r;
        row = row < rows ? row : rows - 1;   // clamp; invalid rows masked below
        lab[r] = labels[row * N + lane];
        sc[r]  = scores[row * N + lane];
    }

    float acc = 0.0f;

    #pragma unroll
    for (int r = 0; r < ROWS_PER_WAVE; ++r) {
        // ---- pass 1: label rank p (strict-< count) ----
        lbuf[w][lane] = lab[r];
        asm volatile("s_waitcnt lgkmcnt(0)" ::: "memory");
        int p0 = 0, p1 = 0, p2 = 0, p3 = 0;
        const float4* lb = (const float4*)lbuf[w];
        #pragma unroll
        for (int kk = 0; kk < N / 4; ++kk) {
            float4 v = lb[kk];               // wave-uniform ds_read_b128 broadcast
            p0 += (v.x < lab[r]);
            p1 += (v.y < lab[r]);
            p2 += (v.z < lab[r]);
            p3 += (v.w < lab[r]);
        }
        const int p = (p0 + p1) + (p2 + p3);

        // ---- u = score - margin * p ----
        const float u = fmaf(-MARGIN, (float)p, sc[r]);

        // ---- pass 2: u rank q ----
        ubuf[w][lane] = u;
        asm volatile("s_waitcnt lgkmcnt(0)" ::: "memory");
        int q0 = 0, q1 = 0, q2 = 0, q3 = 0;
        const float4* ub = (const float4*)ubuf[w];
        #pragma unroll
        for (int kk = 0; kk < N / 4; ++kk) {
            float4 v = ub[kk];
            q0 += (v.x < u);
            q1 += (v.y < u);
            q2 += (v.z < u);
            q3 += (v.w < u);
        }
        const int q = (q0 + q1) + (q2 + q3);

        float contrib = u * (float)(q - p);
        acc += (row0 + r < rows) ? contrib : 0.0f;
    }

    // ---- wave reduction ----
    #pragma unroll
    for (int off = 32; off > 0; off >>= 1)
        acc += __shfl_down(acc, off, 64);

    if (lane == 0) wsum[w] = acc;
    __syncthreads();
    if (threadIdx.x == 0) {
        float s = 0.0f;
        #pragma unroll
        for (int i = 0; i < WAVES_PER_BLOCK; ++i) s += wsum[i];
        atomicAdd(out, s * (1.0f / (float)rows));
    }
}

extern "C" void kernel_launch(void* const* d_in, const int* in_sizes, int n_in,
                              void* d_out, int out_size, void* d_ws, size_t ws_size,
                              hipStream_t stream) {
    const float* scores = (const float*)d_in[0];
    const float* labels = (const float*)d_in[1];
    float* out = (float*)d_out;
    const int rows = in_sizes[0] / N;   // 32768

    hipMemsetAsync(out, 0, sizeof(float), stream);

    const int rows_per_block = WAVES_PER_BLOCK * ROWS_PER_WAVE;   // 16
    const int grid = (rows + rows_per_block - 1) / rows_per_block; // 2048
    mmrl_kernel<<<grid, 256, 0, stream>>>(scores, labels, out, rows);
}

// Round 4
// 94.361 us; speedup vs baseline: 1.3495x; 1.0166x over previous
//
#include <hip/hip_runtime.h>

#define N 64
#define MARGIN 0.1f
#define WAVES_PER_BLOCK 4

// closed form (verified R2, absmax 0.0): row_loss = sum_e u_e * (q_e - p_e)
//   p_e = #{k: lab_k < lab_e}   (label rank)
//   u_e = sc_e - MARGIN * p_e
//   q_e = #{k: u_k < u_e}       (u rank)
//
// Rank by broadcast-compare: element e's value is made wave-uniform
// (s_load for labels, v_readlane for u); every lane j does
// p_j += (val_e < val_j) — one v_cmp + one carry-add. 64 lanes' ranks
// advance in parallel per element. No LDS, no ballot, no scatter.
__global__ __launch_bounds__(256) void mmrl_kernel(const float* __restrict__ scores,
                                                   const float* __restrict__ labels,
                                                   float* __restrict__ out,
                                                   int rows) {
    const int lane = threadIdx.x & 63;
    const int w    = threadIdx.x >> 6;
    const int gwave = blockIdx.x * WAVES_PER_BLOCK + w;
    const int nwaves = gridDim.x * WAVES_PER_BLOCK;

    float acc = 0.0f;

    for (int row = gwave; row < rows; row += nwaves) {
        // wave-uniform row base -> scalar (s_load) broadcasts for labels[rbase+e]
        const int rbase = __builtin_amdgcn_readfirstlane(row) * N;
        const float labv = labels[rbase + lane];   // per-lane copy (coalesced)
        const float scv  = scores[rbase + lane];

        // ---- pass 1: label rank p (strict <) ----
        int pa = 0, pb = 0;                        // 2 chains for vcc ILP
        #pragma unroll
        for (int e = 0; e < N; e += 2) {
            const float le0 = labels[rbase + e];       // uniform -> s_load
            const float le1 = labels[rbase + e + 1];
            pa += (le0 < labv) ? 1 : 0;
            pb += (le1 < labv) ? 1 : 0;
        }
        const int pv = pa + pb;

        const float u = fmaf(-MARGIN, (float)pv, scv);
        const int ubits = __float_as_int(u);

        // ---- pass 2: u rank q ----
        int qa = 0, qb = 0;
        #pragma unroll
        for (int e = 0; e < N; e += 2) {
            const float u0 = __int_as_float(__builtin_amdgcn_readlane(ubits, e));
            const float u1 = __int_as_float(__builtin_amdgcn_readlane(ubits, e + 1));
            qa += (u0 < u) ? 1 : 0;
            qb += (u1 < u) ? 1 : 0;
        }
        const int qv = qa + qb;

        acc = fmaf(u, (float)(qv - pv), acc);
    }

    // ---- wave reduction ----
    #pragma unroll
    for (int off = 32; off > 0; off >>= 1)
        acc += __shfl_down(acc, off, 64);

    __shared__ float wsum[WAVES_PER_BLOCK];
    if (lane == 0) wsum[w] = acc;
    __syncthreads();
    if (threadIdx.x == 0) {
        float s = 0.0f;
        #pragma unroll
        for (int i = 0; i < WAVES_PER_BLOCK; ++i) s += wsum[i];
        atomicAdd(out, s * (1.0f / (float)rows));
    }
}

extern "C" void kernel_launch(void* const* d_in, const int* in_sizes, int n_in,
                              void* d_out, int out_size, void* d_ws, size_t ws_size,
                              hipStream_t stream) {
    const float* scores = (const float*)d_in[0];
    const float* labels = (const float*)d_in[1];
    float* out = (float*)d_out;
    const int rows = in_sizes[0] / N;   // 32768

    (void)hipMemsetAsync(out, 0, sizeof(float), stream);

    // 2048 blocks x 4 waves = 8192 waves, grid-stride 4 rows each
    mmrl_kernel<<<2048, 256, 0, stream>>>(scores, labels, out, rows);
}

// Round 5
// 87.524 us; speedup vs baseline: 1.4549x; 1.0781x over previous
//
#include <hip/hip_runtime.h>

#define N 64
#define MARGIN 0.1f
#define WAVES_PER_BLOCK 4
#define NBLOCKS 2048

// closed form (verified R2/R4, absmax 0.0): row_loss = sum_e u_e * (q_e - p_e)
//   p_e = #{k: lab_k < lab_e},  u_e = sc_e - MARGIN*p_e,  q_e = #{k: u_k < u_e}
//
// R5: (a) no global atomic -- per-block partials to d_ws + tiny reduce kernel
//     (b) 2 rows interleaved per wave iteration, even/odd split counter
//         chains (>=4 independent cmp/add chains to hide vcc/SGPR hazards)
//     (c) pass-1 broadcasts as uniform float4 loads (s_load_dwordx4)
__global__ __launch_bounds__(256) void mmrl_partial(const float* __restrict__ scores,
                                                    const float* __restrict__ labels,
                                                    float* __restrict__ partial,
                                                    int rows) {
    const int lane = threadIdx.x & 63;
    const int w    = threadIdx.x >> 6;
    const int gwave = blockIdx.x * WAVES_PER_BLOCK + w;
    const int nwaves = gridDim.x * WAVES_PER_BLOCK;

    float acc = 0.0f;

    for (int row0 = gwave * 2; row0 < rows; row0 += nwaves * 2) {
        const int rA = row0;
        const int rB = (row0 + 1 < rows) ? row0 + 1 : row0;   // clamp, mask later
        const int baseA = __builtin_amdgcn_readfirstlane(rA) * N;
        const int baseB = __builtin_amdgcn_readfirstlane(rB) * N;

        const float labA = labels[baseA + lane];
        const float labB = labels[baseB + lane];
        const float scA  = scores[baseA + lane];
        const float scB  = scores[baseB + lane];

        // ---- pass 1: label ranks (uniform float4 broadcasts -> s_load_dwordx4) ----
        const float4* A4 = (const float4*)(labels + baseA);
        const float4* B4 = (const float4*)(labels + baseB);
        int pA0 = 0, pA1 = 0, pB0 = 0, pB1 = 0;
        #pragma unroll
        for (int kk = 0; kk < N / 4; ++kk) {
            const float4 a = A4[kk];
            const float4 b = B4[kk];
            pA0 += (a.x < labA) + (a.z < labA);
            pA1 += (a.y < labA) + (a.w < labA);
            pB0 += (b.x < labB) + (b.z < labB);
            pB1 += (b.y < labB) + (b.w < labB);
        }
        const int pA = pA0 + pA1;
        const int pB = pB0 + pB1;

        const float uA = fmaf(-MARGIN, (float)pA, scA);
        const float uB = fmaf(-MARGIN, (float)pB, scB);
        const int uAb = __float_as_int(uA);
        const int uBb = __float_as_int(uB);

        // ---- pass 2: u ranks (readlane broadcasts, 4 independent chains) ----
        int qA0 = 0, qA1 = 0, qB0 = 0, qB1 = 0;
        #pragma unroll
        for (int e = 0; e < N; e += 2) {
            const float a0 = __int_as_float(__builtin_amdgcn_readlane(uAb, e));
            const float a1 = __int_as_float(__builtin_amdgcn_readlane(uAb, e + 1));
            const float b0 = __int_as_float(__builtin_amdgcn_readlane(uBb, e));
            const float b1 = __int_as_float(__builtin_amdgcn_readlane(uBb, e + 1));
            qA0 += (a0 < uA);
            qA1 += (a1 < uA);
            qB0 += (b0 < uB);
            qB1 += (b1 < uB);
        }
        const int qA = qA0 + qA1;
        const int qB = qB0 + qB1;

        acc = fmaf(uA, (float)(qA - pA), acc);
        const float cB = fmaf(uB, (float)(qB - pB), 0.0f);
        acc += (row0 + 1 < rows) ? cB : 0.0f;
    }

    // ---- wave reduction ----
    #pragma unroll
    for (int off = 32; off > 0; off >>= 1)
        acc += __shfl_down(acc, off, 64);

    __shared__ float wsum[WAVES_PER_BLOCK];
    if (lane == 0) wsum[w] = acc;
    __syncthreads();
    if (threadIdx.x == 0) {
        float s = 0.0f;
        #pragma unroll
        for (int i = 0; i < WAVES_PER_BLOCK; ++i) s += wsum[i];
        partial[blockIdx.x] = s;          // plain store, no atomic
    }
}

__global__ __launch_bounds__(256) void mmrl_reduce(const float* __restrict__ partial,
                                                   float* __restrict__ out,
                                                   int npartial, float inv_rows) {
    const int t = threadIdx.x;
    float s = 0.0f;
    for (int i = t; i < npartial; i += 256)
        s += partial[i];
    #pragma unroll
    for (int off = 32; off > 0; off >>= 1)
        s += __shfl_down(s, off, 64);
    __shared__ float wsum[4];
    if ((t & 63) == 0) wsum[t >> 6] = s;
    __syncthreads();
    if (t == 0)
        out[0] = (wsum[0] + wsum[1] + wsum[2] + wsum[3]) * inv_rows;
}

extern "C" void kernel_launch(void* const* d_in, const int* in_sizes, int n_in,
                              void* d_out, int out_size, void* d_ws, size_t ws_size,
                              hipStream_t stream) {
    const float* scores = (const float*)d_in[0];
    const float* labels = (const float*)d_in[1];
    float* out = (float*)d_out;
    float* partial = (float*)d_ws;        // 2048 floats = 8 KB << ws_size
    const int rows = in_sizes[0] / N;     // 32768

    mmrl_partial<<<NBLOCKS, 256, 0, stream>>>(scores, labels, partial, rows);
    mmrl_reduce<<<1, 256, 0, stream>>>(partial, out, NBLOCKS, 1.0f / (float)rows);
}